// Round 10
// baseline (108.489 us; speedup 1.0000x reference)
//
#include <hip/hip_runtime.h>
#include <math.h>

typedef _Float16 f16x8 __attribute__((ext_vector_type(8)));
typedef _Float16 f16x2 __attribute__((ext_vector_type(2)));
typedef float    f32x4 __attribute__((ext_vector_type(4)));

union F16x8u { f16x8 v; f16x2 h[4]; };

// v_sin_f32 / v_cos_f32 take REVOLUTIONS: sin(2*pi*x) = v_sin(x).
__device__ __forceinline__ float cos1_hw(float x) { return __builtin_amdgcn_cosf(x); }
__device__ __forceinline__ float sin1_hw(float x) { return __builtin_amdgcn_sinf(x); }

// v_cvt_pkrtz_f16_f32 returns a __fp16 vector; bit-cast to our _Float16 pair.
__device__ __forceinline__ f16x2 pkrtz(float a, float b)
{
    return __builtin_bit_cast(f16x2, __builtin_amdgcn_cvt_pkrtz(a, b));
}

// ---------------------------------------------------------------------------
// ROUND 16 = COUNTER-SURFACING DIAGNOSTIC (rep x2) + pk-f16 revert.
// r15 (packed-f16 interp) was perf-NULL and doubled absmax -> reverted to the
// r14 f32 interp. Model status: MFMA floor ~8.7us, VALU ~4.5us, measured
// kernel ~31.6us -- a 3.6x stall factor that survived three different
// instruction mixes. The kernel has NEVER been profiled (31.6us < the 40.3us
// fill cutoff in top-5). This round wraps the post-staging body in an
// idempotent rep x2 loop: one dispatch ~63us -> tops the profile with full
// MfmaUtil / VALUBusy / Occupancy / VGPR / bank-conflict counters.
// rep boundary barrier orders rep2's Trl/FrL rewrites vs rep1's readers;
// outputs identical both reps. Cost: +~31us this round only; counters decide
// round 17 (decision table in session notes).
// ---------------------------------------------------------------------------

__global__ __launch_bounds__(1024, 4)
void fourier_fused(const float* __restrict__ y,
                   const float* __restrict__ xnew,
                   float* __restrict__ out)
{
    __shared__ _Float16 Yt [64 * 72];    // Y^T f16: Yt[n2][n1], pitch 72
    __shared__ _Float16 Trl[64 * 72];    // T re: Trl[k][n2]
    __shared__ _Float16 Til[64 * 72];    // T im
    __shared__ _Float16 FrL[64 * 72];    // F^T re: FrL[m][k]
    __shared__ _Float16 FiL[64 * 72];    // F^T im
    __shared__ float2   XY[2048];        // sample coords
    __shared__ float2   tw[64];          // (cos, sin)(2pi n/64)

    const int tid   = threadIdx.x;
    const int batch = blockIdx.x >> 3;
    const int sgrp  = blockIdx.x & 7;                 // 8 blocks per batch
    const int pbase = (batch << 14) + (sgrp << 11);   // 2048 points

    // ---- stage xnew + y (transposed f16) + twiddles ----
    ((float4*)XY)[tid] = ((const float4*)(xnew + ((size_t)pbase << 1)))[tid];
    {
        const float4 v = ((const float4*)(y + (batch << 12)))[tid];
        const int n1 = tid >> 4;            // row of y
        const int n2 = (tid & 15) << 2;     // col base
        Yt[(n2 + 0) * 72 + n1] = (_Float16)v.x;
        Yt[(n2 + 1) * 72 + n1] = (_Float16)v.y;
        Yt[(n2 + 2) * 72 + n1] = (_Float16)v.z;
        Yt[(n2 + 3) * 72 + n1] = (_Float16)v.w;
    }
    if (tid < 64) {
        const float a = (float)tid * (1.0f / 64.0f);
        tw[tid] = make_float2(cos1_hw(a), sin1_hw(a));
    }
    __syncthreads();

    const int lane = tid & 63;
    const int wv   = tid >> 6;           // 0..15
    const int quad = lane >> 4;
    const int lrow = lane & 15;

    // ==== DIAGNOSTIC rep x2: identical work, identical outputs ====
#pragma unroll 1
    for (int rep = 0; rep < 2; ++rep) {
        if (rep) __syncthreads();        // order rep2 writes vs rep1 readers

        // ---- DFT pass A (MFMA): T[k][n2] = sum_n1 W[k][n1] Y[n1][n2] ----
        {
            const int rt   = wv >> 2;
            const int ct   = wv & 3;
            const int krow = (rt << 4) + lrow;
            f32x4 Tr = (f32x4){0.f, 0.f, 0.f, 0.f};
            f32x4 Ti = (f32x4){0.f, 0.f, 0.f, 0.f};
#pragma unroll
            for (int kt = 0; kt < 2; ++kt) {
                const int n1b = (kt << 5) + (quad << 3);
                F16x8u cf, sn;                  // cos, -sin  (W = c - i s)
#pragma unroll
                for (int jp = 0; jp < 4; ++jp) {
                    const float2 wa = tw[(krow * (n1b + 2 * jp    )) & 63];
                    const float2 wb = tw[(krow * (n1b + 2 * jp + 1)) & 63];
                    cf.h[jp] = pkrtz(wa.x, wb.x);
                    sn.h[jp] = pkrtz(-wa.y, -wb.y);
                }
                const f16x8 yf = *(const f16x8*)&Yt[((ct << 4) + lrow) * 72 + n1b];
                Tr = __builtin_amdgcn_mfma_f32_16x16x32_f16(cf.v, yf, Tr, 0, 0, 0);
                Ti = __builtin_amdgcn_mfma_f32_16x16x32_f16(sn.v, yf, Ti, 0, 0, 0);
            }
#pragma unroll
            for (int reg = 0; reg < 4; ++reg) {
                const int k = (rt << 4) + (quad << 2) + reg;
                Trl[k * 72 + (ct << 4) + lrow] = (_Float16)Tr[reg];
                Til[k * 72 + (ct << 4) + lrow] = (_Float16)Ti[reg];
            }
        }
        __syncthreads();

        // ---- DFT pass B (MFMA): F^T[m][k] = sum_n2 W2[m][n2] T^T[n2][k] ----
        {
            const int mt2 = wv >> 2;
            const int ct2 = wv & 3;
            const int mrow = (mt2 << 4) + lrow;
            f32x4 Fr = (f32x4){0.f, 0.f, 0.f, 0.f};
            f32x4 Fi = (f32x4){0.f, 0.f, 0.f, 0.f};
#pragma unroll
            for (int kt = 0; kt < 2; ++kt) {
                const int n2b = (kt << 5) + (quad << 3);
                F16x8u cf, sf, sn;
#pragma unroll
                for (int jp = 0; jp < 4; ++jp) {
                    const float2 wa = tw[(mrow * (n2b + 2 * jp    )) & 63];
                    const float2 wb = tw[(mrow * (n2b + 2 * jp + 1)) & 63];
                    cf.h[jp] = pkrtz(wa.x, wb.x);
                    sf.h[jp] = pkrtz(wa.y, wb.y);
                    sn.h[jp] = pkrtz(-wa.y, -wb.y);
                }
                const f16x8 btr = *(const f16x8*)&Trl[((ct2 << 4) + lrow) * 72 + n2b];
                const f16x8 bti = *(const f16x8*)&Til[((ct2 << 4) + lrow) * 72 + n2b];
                Fr = __builtin_amdgcn_mfma_f32_16x16x32_f16(cf.v, btr, Fr, 0, 0, 0);
                Fr = __builtin_amdgcn_mfma_f32_16x16x32_f16(sf.v, bti, Fr, 0, 0, 0);
                Fi = __builtin_amdgcn_mfma_f32_16x16x32_f16(cf.v, bti, Fi, 0, 0, 0);
                Fi = __builtin_amdgcn_mfma_f32_16x16x32_f16(sn.v, btr, Fi, 0, 0, 0);
            }
#pragma unroll
            for (int reg = 0; reg < 4; ++reg) {
                const int m = (mt2 << 4) + (quad << 2) + reg;
                FrL[m * 72 + (ct2 << 4) + lrow] = (_Float16)Fr[reg];
                FiL[m * 72 + (ct2 << 4) + lrow] = (_Float16)Fi[reg];
            }
        }
        __syncthreads();

        // ---- hoist A-operand (F^T) fragments once per wave ----
        f16x8 Ar[4][2], Ai[4][2];
#pragma unroll
        for (int nt = 0; nt < 4; ++nt)
#pragma unroll
            for (int kt = 0; kt < 2; ++kt) {
                const int off = ((nt << 4) + lrow) * 72 + (kt << 5) + (quad << 3);
                Ar[nt][kt] = *(const f16x8*)&FrL[off];
                Ai[nt][kt] = *(const f16x8*)&FiL[off];
            }

        // ---- interp: G[p,m] = sum_k F[k,m] E1[p,k] (MFMA);
        //      red = Re sum_m G[p,m] E2[p,m] (f32 VALU, r14-proven) ----
#pragma unroll 1
        for (int mt = 0; mt < 8; ++mt) {
            const int lpt = ((mt >> 1) << 9) + (wv << 5) + ((mt & 1) << 4);
            const float2 xv = XY[lpt + lrow];

            const float cs1 = cos1_hw(xv.x);
            const float sn1 = sin1_hw(xv.x);
            const float cs1b = fmaf(cs1, cs1, -(sn1 * sn1));
            const float sn1b = 2.0f * cs1 * sn1;

            f32x4 Gr[4], Gi[4];
#pragma unroll
            for (int nt = 0; nt < 4; ++nt) {
                Gr[nt] = (f32x4){0.f, 0.f, 0.f, 0.f};
                Gi[nt] = (f32x4){0.f, 0.f, 0.f, 0.f};
            }

#pragma unroll
            for (int kt = 0; kt < 2; ++kt) {
                const float fb = (float)((quad << 3) - (kt ? 32 : 0));
                float th = xv.x * fb;
                th -= floorf(th);                  // revolutions in [0,1)
                float er0 = cos1_hw(th);
                float ei0 = sin1_hw(th);
                float er1 = fmaf(-ei0, sn1, er0 * cs1);
                float ei1 = fmaf( er0, sn1, ei0 * cs1);

                F16x8u ur, ui, un;                 // E1r, E1i, -E1i
#pragma unroll
                for (int jp = 0; jp < 4; ++jp) {
                    ur.h[jp] = pkrtz(er0, er1);
                    ui.h[jp] = pkrtz(ei0, ei1);
                    un.h[jp] = pkrtz(-ei0, -ei1);
                    if (jp < 3) {
                        const float e0 = fmaf(-ei0, sn1b, er0 * cs1b);
                        ei0 = fmaf(er0, sn1b, ei0 * cs1b);
                        er0 = e0;
                        const float e1 = fmaf(-ei1, sn1b, er1 * cs1b);
                        ei1 = fmaf(er1, sn1b, ei1 * cs1b);
                        er1 = e1;
                    }
                }
#pragma unroll
                for (int nt = 0; nt < 4; ++nt) {
                    Gr[nt] = __builtin_amdgcn_mfma_f32_16x16x32_f16(Ar[nt][kt], ur.v, Gr[nt], 0, 0, 0);
                    Gr[nt] = __builtin_amdgcn_mfma_f32_16x16x32_f16(Ai[nt][kt], un.v, Gr[nt], 0, 0, 0);
                    Gi[nt] = __builtin_amdgcn_mfma_f32_16x16x32_f16(Ar[nt][kt], ui.v, Gi[nt], 0, 0, 0);
                    Gi[nt] = __builtin_amdgcn_mfma_f32_16x16x32_f16(Ai[nt][kt], ur.v, Gi[nt], 0, 0, 0);
                }
            }

            // ---- stage B: red = Re sum_m G[p,m] e^{2pi i x2 f(m)} ----
            const float cs2 = cos1_hw(xv.y);
            const float sn2 = sin1_hw(xv.y);
            float t16 = xv.y * 16.0f;
            t16 -= floorf(t16);
            const float c16 = cos1_hw(t16);
            const float s16 = sin1_hw(t16);
            const float cm32 = fmaf(c16, c16, -(s16 * s16));   // conj(rot16^2)
            const float sm32 = -2.0f * c16 * s16;

            float thA = xv.y * (float)(quad << 2);
            thA -= floorf(thA);
            const float erA = cos1_hw(thA);
            const float eiA = sin1_hw(thA);

            float br[4], bi[4];
            br[0] = erA;                            bi[0] = eiA;
            br[1] = fmaf(-eiA, s16, erA * c16);     bi[1] = fmaf(erA, s16, eiA * c16);
            br[2] = fmaf(-eiA, sm32, erA * cm32);   bi[2] = fmaf(erA, sm32, eiA * cm32);
            br[3] = fmaf(-bi[2], s16, br[2] * c16); bi[3] = fmaf(br[2], s16, bi[2] * c16);

            float red = 0.0f;
#pragma unroll
            for (int nt = 0; nt < 4; ++nt) {
                float er = br[nt];
                float ei = bi[nt];
#pragma unroll
                for (int reg = 0; reg < 4; ++reg) {
                    red = fmaf(Gr[nt][reg],  er, red);
                    red = fmaf(Gi[nt][reg], -ei, red);
                    if (reg < 3) {
                        const float t2 = fmaf(-ei, sn2, er * cs2);
                        ei = fmaf(er, sn2, ei * cs2);
                        er = t2;
                    }
                }
            }
            red += __shfl_xor(red, 16, 64);
            red += __shfl_xor(red, 32, 64);
            if (lane < 16)
                out[pbase + lpt + lane] = red * (1.0f / 4096.0f);
        }
    }   // rep
}

extern "C" void kernel_launch(void* const* d_in, const int* in_sizes, int n_in,
                              void* d_out, int out_size, void* d_ws, size_t ws_size,
                              hipStream_t stream)
{
    const float* y    = (const float*)d_in[0];   // [32, 64, 64]
    const float* xnew = (const float*)d_in[1];   // [32, 128, 128, 2]
    float* out        = (float*)d_out;           // [32, 128, 128]

    // ONE dispatch: 32 batches x 8 segment-groups = 256 blocks = 1 per CU.
    fourier_fused<<<256, 1024, 0, stream>>>(y, xnew, out);
}

// Round 11
// 77.103 us; speedup vs baseline: 1.4071x; 1.4071x over previous
//
#include <hip/hip_runtime.h>
#include <math.h>

typedef _Float16 f16x8 __attribute__((ext_vector_type(8)));
typedef _Float16 f16x2 __attribute__((ext_vector_type(2)));
typedef float    f32x4 __attribute__((ext_vector_type(4)));

union F16x8u { f16x8 v; f16x2 h[4]; };

// v_sin_f32 / v_cos_f32 take REVOLUTIONS: sin(2*pi*x) = v_sin(x).
__device__ __forceinline__ float cos1_hw(float x) { return __builtin_amdgcn_cosf(x); }
__device__ __forceinline__ float sin1_hw(float x) { return __builtin_amdgcn_sinf(x); }

// v_cvt_pkrtz_f16_f32 returns a __fp16 vector; bit-cast to our _Float16 pair.
__device__ __forceinline__ f16x2 pkrtz(float a, float b)
{
    return __builtin_bit_cast(f16x2, __builtin_amdgcn_cvt_pkrtz(a, b));
}

// ---------------------------------------------------------------------------
// ROUND 17 = LATENCY DE-SERIALIZATION.
// r16 rep-x2 profile (first production counters): kernel ~30.8us/rep,
// MfmaUtil 22.5, VALUBusy 45.9, Occupancy 34, bank-conflicts minor, HBM 11%.
// Accounting: VALU 14us + MFMA 7us + ~10us NO-ISSUE stall. Cause theory:
// (1) 16 waves leave the barrier in lockstep, execute identical code ->
//     trans-latency heads / MFMA blocks / serial tails align across the
//     4 waves of each SIMD -> bubbles can't interleave.
// (2) per-mt serial tail: 32-deep dependent red-FMA chain (~190cy, AGPR
//     reads) + 2 dependent shfls (~80cy).
// Fixes (math untouched): de-sync wave mt-order by 2*(wv>>2) so same-SIMD
// waves run different phases; split red into 4 per-nt partials + tree
// combine (serial depth 32 -> 10). rep loop removed (production).
// Predicted: kernel -> 23-27us, dur ~69-72, VALUBusy -> 55-60.
// ---------------------------------------------------------------------------

__global__ __launch_bounds__(1024, 4)
void fourier_fused(const float* __restrict__ y,
                   const float* __restrict__ xnew,
                   float* __restrict__ out)
{
    __shared__ _Float16 Yt [64 * 72];    // Y^T f16: Yt[n2][n1], pitch 72
    __shared__ _Float16 Trl[64 * 72];    // T re: Trl[k][n2]
    __shared__ _Float16 Til[64 * 72];    // T im
    __shared__ _Float16 FrL[64 * 72];    // F^T re: FrL[m][k]
    __shared__ _Float16 FiL[64 * 72];    // F^T im
    __shared__ float2   XY[2048];        // sample coords
    __shared__ float2   tw[64];          // (cos, sin)(2pi n/64)

    const int tid   = threadIdx.x;
    const int batch = blockIdx.x >> 3;
    const int sgrp  = blockIdx.x & 7;                 // 8 blocks per batch
    const int pbase = (batch << 14) + (sgrp << 11);   // 2048 points

    // ---- stage xnew + y (transposed f16) + twiddles ----
    ((float4*)XY)[tid] = ((const float4*)(xnew + ((size_t)pbase << 1)))[tid];
    {
        const float4 v = ((const float4*)(y + (batch << 12)))[tid];
        const int n1 = tid >> 4;            // row of y
        const int n2 = (tid & 15) << 2;     // col base
        Yt[(n2 + 0) * 72 + n1] = (_Float16)v.x;
        Yt[(n2 + 1) * 72 + n1] = (_Float16)v.y;
        Yt[(n2 + 2) * 72 + n1] = (_Float16)v.z;
        Yt[(n2 + 3) * 72 + n1] = (_Float16)v.w;
    }
    if (tid < 64) {
        const float a = (float)tid * (1.0f / 64.0f);
        tw[tid] = make_float2(cos1_hw(a), sin1_hw(a));
    }
    __syncthreads();

    const int lane = tid & 63;
    const int wv   = tid >> 6;           // 0..15
    const int quad = lane >> 4;
    const int lrow = lane & 15;

    // ---- DFT pass A (MFMA): T[k][n2] = sum_n1 W[k][n1] Y[n1][n2] ----
    {
        const int rt   = wv >> 2;
        const int ct   = wv & 3;
        const int krow = (rt << 4) + lrow;
        f32x4 Tr = (f32x4){0.f, 0.f, 0.f, 0.f};
        f32x4 Ti = (f32x4){0.f, 0.f, 0.f, 0.f};
#pragma unroll
        for (int kt = 0; kt < 2; ++kt) {
            const int n1b = (kt << 5) + (quad << 3);
            F16x8u cf, sn;                  // cos, -sin  (W = c - i s)
#pragma unroll
            for (int jp = 0; jp < 4; ++jp) {
                const float2 wa = tw[(krow * (n1b + 2 * jp    )) & 63];
                const float2 wb = tw[(krow * (n1b + 2 * jp + 1)) & 63];
                cf.h[jp] = pkrtz(wa.x, wb.x);
                sn.h[jp] = pkrtz(-wa.y, -wb.y);
            }
            const f16x8 yf = *(const f16x8*)&Yt[((ct << 4) + lrow) * 72 + n1b];
            Tr = __builtin_amdgcn_mfma_f32_16x16x32_f16(cf.v, yf, Tr, 0, 0, 0);
            Ti = __builtin_amdgcn_mfma_f32_16x16x32_f16(sn.v, yf, Ti, 0, 0, 0);
        }
#pragma unroll
        for (int reg = 0; reg < 4; ++reg) {
            const int k = (rt << 4) + (quad << 2) + reg;
            Trl[k * 72 + (ct << 4) + lrow] = (_Float16)Tr[reg];
            Til[k * 72 + (ct << 4) + lrow] = (_Float16)Ti[reg];
        }
    }
    __syncthreads();

    // ---- DFT pass B (MFMA): F^T[m][k] = sum_n2 W2[m][n2] T^T[n2][k] ----
    {
        const int mt2 = wv >> 2;
        const int ct2 = wv & 3;
        const int mrow = (mt2 << 4) + lrow;
        f32x4 Fr = (f32x4){0.f, 0.f, 0.f, 0.f};
        f32x4 Fi = (f32x4){0.f, 0.f, 0.f, 0.f};
#pragma unroll
        for (int kt = 0; kt < 2; ++kt) {
            const int n2b = (kt << 5) + (quad << 3);
            F16x8u cf, sf, sn;
#pragma unroll
            for (int jp = 0; jp < 4; ++jp) {
                const float2 wa = tw[(mrow * (n2b + 2 * jp    )) & 63];
                const float2 wb = tw[(mrow * (n2b + 2 * jp + 1)) & 63];
                cf.h[jp] = pkrtz(wa.x, wb.x);
                sf.h[jp] = pkrtz(wa.y, wb.y);
                sn.h[jp] = pkrtz(-wa.y, -wb.y);
            }
            const f16x8 btr = *(const f16x8*)&Trl[((ct2 << 4) + lrow) * 72 + n2b];
            const f16x8 bti = *(const f16x8*)&Til[((ct2 << 4) + lrow) * 72 + n2b];
            Fr = __builtin_amdgcn_mfma_f32_16x16x32_f16(cf.v, btr, Fr, 0, 0, 0);
            Fr = __builtin_amdgcn_mfma_f32_16x16x32_f16(sf.v, bti, Fr, 0, 0, 0);
            Fi = __builtin_amdgcn_mfma_f32_16x16x32_f16(cf.v, bti, Fi, 0, 0, 0);
            Fi = __builtin_amdgcn_mfma_f32_16x16x32_f16(sn.v, btr, Fi, 0, 0, 0);
        }
#pragma unroll
        for (int reg = 0; reg < 4; ++reg) {
            const int m = (mt2 << 4) + (quad << 2) + reg;
            FrL[m * 72 + (ct2 << 4) + lrow] = (_Float16)Fr[reg];
            FiL[m * 72 + (ct2 << 4) + lrow] = (_Float16)Fi[reg];
        }
    }
    __syncthreads();

    // ---- hoist A-operand (F^T) fragments once per wave ----
    f16x8 Ar[4][2], Ai[4][2];
#pragma unroll
    for (int nt = 0; nt < 4; ++nt)
#pragma unroll
        for (int kt = 0; kt < 2; ++kt) {
            const int off = ((nt << 4) + lrow) * 72 + (kt << 5) + (quad << 3);
            Ar[nt][kt] = *(const f16x8*)&FrL[off];
            Ai[nt][kt] = *(const f16x8*)&FiL[off];
        }

    // ---- interp. De-synced tile order: same-SIMD waves (wv = s, s+4, s+8,
    //      s+12) start at mt 0/2/4/6 so heads/MFMA/tails interleave. ----
    const int mt0 = (wv >> 2) << 1;
#pragma unroll 1
    for (int it = 0; it < 8; ++it) {
        const int mt  = (it + mt0) & 7;
        const int lpt = ((mt >> 1) << 9) + (wv << 5) + ((mt & 1) << 4);
        const float2 xv = XY[lpt + lrow];

        const float cs1 = cos1_hw(xv.x);
        const float sn1 = sin1_hw(xv.x);
        const float cs1b = fmaf(cs1, cs1, -(sn1 * sn1));
        const float sn1b = 2.0f * cs1 * sn1;

        f32x4 Gr[4], Gi[4];
#pragma unroll
        for (int nt = 0; nt < 4; ++nt) {
            Gr[nt] = (f32x4){0.f, 0.f, 0.f, 0.f};
            Gi[nt] = (f32x4){0.f, 0.f, 0.f, 0.f};
        }

#pragma unroll
        for (int kt = 0; kt < 2; ++kt) {
            const float fb = (float)((quad << 3) - (kt ? 32 : 0));
            float th = xv.x * fb;
            th -= floorf(th);                  // revolutions in [0,1)
            float er0 = cos1_hw(th);
            float ei0 = sin1_hw(th);
            float er1 = fmaf(-ei0, sn1, er0 * cs1);
            float ei1 = fmaf( er0, sn1, ei0 * cs1);

            F16x8u ur, ui, un;                 // E1r, E1i, -E1i
#pragma unroll
            for (int jp = 0; jp < 4; ++jp) {
                ur.h[jp] = pkrtz(er0, er1);
                ui.h[jp] = pkrtz(ei0, ei1);
                un.h[jp] = pkrtz(-ei0, -ei1);
                if (jp < 3) {
                    const float e0 = fmaf(-ei0, sn1b, er0 * cs1b);
                    ei0 = fmaf(er0, sn1b, ei0 * cs1b);
                    er0 = e0;
                    const float e1 = fmaf(-ei1, sn1b, er1 * cs1b);
                    ei1 = fmaf(er1, sn1b, ei1 * cs1b);
                    er1 = e1;
                }
            }
#pragma unroll
            for (int nt = 0; nt < 4; ++nt) {
                Gr[nt] = __builtin_amdgcn_mfma_f32_16x16x32_f16(Ar[nt][kt], ur.v, Gr[nt], 0, 0, 0);
                Gr[nt] = __builtin_amdgcn_mfma_f32_16x16x32_f16(Ai[nt][kt], un.v, Gr[nt], 0, 0, 0);
                Gi[nt] = __builtin_amdgcn_mfma_f32_16x16x32_f16(Ar[nt][kt], ui.v, Gi[nt], 0, 0, 0);
                Gi[nt] = __builtin_amdgcn_mfma_f32_16x16x32_f16(Ai[nt][kt], ur.v, Gi[nt], 0, 0, 0);
            }
        }

        // ---- stage B: red = Re sum_m G[p,m] e^{2pi i x2 f(m)} ----
        // 4 independent per-nt partial chains (serial depth 8) + tree combine.
        const float cs2 = cos1_hw(xv.y);
        const float sn2 = sin1_hw(xv.y);
        float t16 = xv.y * 16.0f;
        t16 -= floorf(t16);
        const float c16 = cos1_hw(t16);
        const float s16 = sin1_hw(t16);
        const float cm32 = fmaf(c16, c16, -(s16 * s16));   // conj(rot16^2)
        const float sm32 = -2.0f * c16 * s16;

        float thA = xv.y * (float)(quad << 2);
        thA -= floorf(thA);
        const float erA = cos1_hw(thA);
        const float eiA = sin1_hw(thA);

        float br[4], bi[4];
        br[0] = erA;                            bi[0] = eiA;
        br[1] = fmaf(-eiA, s16, erA * c16);     bi[1] = fmaf(erA, s16, eiA * c16);
        br[2] = fmaf(-eiA, sm32, erA * cm32);   bi[2] = fmaf(erA, sm32, eiA * cm32);
        br[3] = fmaf(-bi[2], s16, br[2] * c16); bi[3] = fmaf(br[2], s16, bi[2] * c16);

        float red0 = 0.0f, red1 = 0.0f, red2 = 0.0f, red3 = 0.0f;
#pragma unroll
        for (int nt = 0; nt < 4; ++nt) {
            float er = br[nt];
            float ei = bi[nt];
            float acc = 0.0f;
#pragma unroll
            for (int reg = 0; reg < 4; ++reg) {
                acc = fmaf(Gr[nt][reg],  er, acc);
                acc = fmaf(Gi[nt][reg], -ei, acc);
                if (reg < 3) {
                    const float t2 = fmaf(-ei, sn2, er * cs2);
                    ei = fmaf(er, sn2, ei * cs2);
                    er = t2;
                }
            }
            if (nt == 0) red0 = acc;
            else if (nt == 1) red1 = acc;
            else if (nt == 2) red2 = acc;
            else red3 = acc;
        }
        float red = (red0 + red1) + (red2 + red3);
        red += __shfl_xor(red, 16, 64);
        red += __shfl_xor(red, 32, 64);
        if (lane < 16)
            out[pbase + lpt + lane] = red * (1.0f / 4096.0f);
    }
}

extern "C" void kernel_launch(void* const* d_in, const int* in_sizes, int n_in,
                              void* d_out, int out_size, void* d_ws, size_t ws_size,
                              hipStream_t stream)
{
    const float* y    = (const float*)d_in[0];   // [32, 64, 64]
    const float* xnew = (const float*)d_in[1];   // [32, 128, 128, 2]
    float* out        = (float*)d_out;           // [32, 128, 128]

    // ONE dispatch: 32 batches x 8 segment-groups = 256 blocks = 1 per CU.
    fourier_fused<<<256, 1024, 0, stream>>>(y, xnew, out);
}